// Round 18
// baseline (164.558 us; speedup 1.0000x reference)
//
#include <hip/hip_runtime.h>
#include <hip/hip_bf16.h>

#define B_DIM 4096
#define I_DIM 2048
#define H_DIM 2048

typedef unsigned char u8;
typedef unsigned short u16;
typedef unsigned int u32;
typedef __attribute__((ext_vector_type(4))) float f32x4;
typedef __attribute__((ext_vector_type(4))) int i32x4;
typedef __attribute__((ext_vector_type(8))) int i32x8;

#define SBAR __builtin_amdgcn_sched_barrier(0)

__device__ __forceinline__ void gload_lds16(const void* g, void* l) {
  __builtin_amdgcn_global_load_lds(
      (const __attribute__((address_space(1))) void*)g,
      (__attribute__((address_space(3))) void*)l, 16, 0, 0);
}

// branchless fp4 (e2m1) encoder: quantizes v*inv_scale to e2m1 code
__device__ __forceinline__ u32 f2fp4(float v, float inv_scale) {
  const float a = fabsf(v) * inv_scale;
  u32 m = (u32)(a > 0.25f) + (u32)(a > 0.75f) + (u32)(a > 1.25f) +
          (u32)(a > 1.75f) + (u32)(a > 2.5f) + (u32)(a > 3.5f) + (u32)(a > 5.0f);
  return ((__float_as_uint(v) >> 31) << 3) | m;
}

// ---------------------------------------------------------------------------
// Kernel A (fused prep):
//  blocks [0, 512):     coeff -> coeffT fp4 (8 transpose tiles per block);
//                       block 0 also zeroes the strip_done counters
//  blocks [512, 1536):  x -> fp4 xf4; (an,bn) -> fp4-pair ab4
// ---------------------------------------------------------------------------
__global__ void prep_all(const float* __restrict__ x, const float* __restrict__ coeff,
                         const float* __restrict__ an, const float* __restrict__ bn,
                         u16* __restrict__ xf4, u16* __restrict__ ct4,
                         u32* __restrict__ ab4, u32* __restrict__ strip_done) {
  if (blockIdx.x < 512) {
    if (blockIdx.x == 0 && threadIdx.x < 32) strip_done[threadIdx.x] = 0;
    __shared__ float tile[32][33];
    const int tid = threadIdx.x;
    const int tx = tid & 31;
    const int ty = tid >> 5;
    const int hl = tid >> 3;
    const int q = (tid & 7) * 4;
#pragma unroll
    for (int rep = 0; rep < 8; ++rep) {
      const int tidx = blockIdx.x * 8 + rep;      // 0..4095
      const int h0 = (tidx & 63) * 32;
      const int i0 = (tidx >> 6) * 32;
      for (int r = ty; r < 32; r += 8)
        tile[r][tx] = coeff[(long)(i0 + r) * H_DIM + (h0 + tx)];
      __syncthreads();
      u32 w = f2fp4(tile[q + 0][hl], 8.f) | (f2fp4(tile[q + 1][hl], 8.f) << 4) |
              (f2fp4(tile[q + 2][hl], 8.f) << 8) | (f2fp4(tile[q + 3][hl], 8.f) << 12);
      ct4[(long)(h0 + hl) * (I_DIM / 4) + ((i0 + q) >> 2)] = (u16)w;
      __syncthreads();  // protect tile before next rep's load
    }
    return;
  }
  const long NX4 = (long)B_DIM * I_DIM / 4;
  const long NA4 = (long)I_DIM * H_DIM / 4;
  const long total = NX4 + NA4;
  const long stride = (long)1024 * blockDim.x;
  for (long t = (long)(blockIdx.x - 512) * blockDim.x + threadIdx.x; t < total;
       t += stride) {
    if (t < NX4) {
      float4 v = *(const float4*)(x + t * 4);
      u32 b0 = f2fp4(v.x, 1.f) | (f2fp4(v.y, 1.f) << 4);
      u32 b1 = f2fp4(v.z, 1.f) | (f2fp4(v.w, 1.f) << 4);
      xf4[t] = (u16)(b0 | (b1 << 8));
    } else {
      long p = (t - NX4) * 4;
      float4 va = *(const float4*)(an + p);
      float4 vb = *(const float4*)(bn + p);
      u32 b0 = f2fp4(va.x, 8.f) | (f2fp4(vb.x, 8.f) << 4);
      u32 b1 = f2fp4(va.y, 8.f) | (f2fp4(vb.y, 8.f) << 4);
      u32 b2 = f2fp4(va.z, 8.f) | (f2fp4(vb.z, 8.f) << 4);
      u32 b3 = f2fp4(va.w, 8.f) | (f2fp4(vb.w, 8.f) << 4);
      ab4[p >> 2] = b0 | (b1 << 8) | (b2 << 16) | (b3 << 24);
    }
  }
}

// ---------------------------------------------------------------------------
// fp4 GEMM kloop (verified): 128x128 tile, K-step 128 B, dbuf 64 KB,
// depth-2 prefetch, counted vmcnt(8), two barriers/iter, XOR swizzle.
// ---------------------------------------------------------------------------
__device__ __forceinline__ void stage_tile(const char* Ab, const char* Bb, long kbyte,
                                           long lda, long ldb, char* AsB, char* BsB,
                                           int tid) {
#pragma unroll
  for (int i = 0; i < 4; ++i) {
    const int o = i * 4096 + tid * 16;
    const int row = o >> 7;
    const int ls = ((((o >> 4) & 7) ^ (row & 7)) << 4);
    gload_lds16(Ab + (long)row * lda + kbyte + ls, AsB + o);
  }
#pragma unroll
  for (int i = 0; i < 4; ++i) {
    const int o = i * 4096 + tid * 16;
    const int row = o >> 7;
    const int ls = ((((o >> 4) & 7) ^ (row & 7)) << 4);
    gload_lds16(Bb + (long)row * ldb + kbyte + ls, BsB + o);
  }
}

__device__ __forceinline__ i32x4 frag_ld16(const char* S, int row, int slot) {
  return *(const i32x4*)(S + row * 128 + ((slot ^ (row & 7)) << 4));
}

template <int SA, int SB>
__device__ __forceinline__ void gemm_kloop_fp4(const char* __restrict__ A,
                                               const char* __restrict__ Bt,
                                               int rowA0, int colB0, long Kbytes,
                                               char* smem, f32x4 acc[4][4]) {
  const int tid = threadIdx.x;
  const int lane = tid & 63;
  const int wid = tid >> 6;
  const int wr = wid >> 1, wc = wid & 1;
  const long lda = Kbytes, ldb = Kbytes;
  const char* Ab = A + (long)rowA0 * lda;
  const char* Bb = Bt + (long)colB0 * ldb;
  const int arow = wr * 64 + (lane & 15);
  const int brow = wc * 64 + (lane & 15);
  const int g = lane >> 4;  // 0..3
  const int nt = (int)(Kbytes >> 7);
  char* AsB = smem;           // A tiles @ 0, 32768
  char* BsB = smem + 16384;   // B tiles @ 16384, 49152

  stage_tile(Ab, Bb, 0, lda, ldb, AsB, BsB, tid);
  stage_tile(Ab, Bb, 128, lda, ldb, AsB + 32768, BsB + 32768, tid);

  for (int t = 0; t < nt; ++t) {
    const int cur = (t & 1) << 15;
    if (t < nt - 1) asm volatile("s_waitcnt vmcnt(8)" ::: "memory");
    else            asm volatile("s_waitcnt vmcnt(0)" ::: "memory");
    SBAR;
    __builtin_amdgcn_s_barrier();
    SBAR;

    i32x8 af[8], bfr[8];  // low i32x4 holds the fp4 operand
#pragma unroll
    for (int s = 0; s < 2; ++s)
#pragma unroll
      for (int m = 0; m < 4; ++m) {
        *(i32x4*)&af[s * 4 + m]  = frag_ld16(AsB + cur, arow + m * 16, s * 4 + g);
        *(i32x4*)&bfr[s * 4 + m] = frag_ld16(BsB + cur, brow + m * 16, s * 4 + g);
      }
    asm volatile("s_waitcnt lgkmcnt(0)" ::: "memory");
    SBAR;
    __builtin_amdgcn_s_barrier();  // all waves done reading buf[cur]
    SBAR;

    if (t + 2 < nt)
      stage_tile(Ab, Bb, (long)(t + 2) * 128, lda, ldb, AsB + cur, BsB + cur, tid);

    __builtin_amdgcn_s_setprio(1);
#pragma unroll
    for (int s = 0; s < 2; ++s)
#pragma unroll
      for (int m = 0; m < 4; ++m)
#pragma unroll
        for (int n = 0; n < 4; ++n)
          acc[m][n] = __builtin_amdgcn_mfma_scale_f32_16x16x128_f8f6f4(
              af[s * 4 + m], bfr[s * 4 + n], acc[m][n], 4, 4, 0, SA, 0, SB);
    __builtin_amdgcn_s_setprio(0);
    SBAR;
  }
}

// Square XCD chunking: 512 blocks over 32(by) x 16(bx); each XCD owns an
// 8x8 square chunk -> per-XCD working set fits the 4 MB L2.
__device__ __forceinline__ void tile_xy(int& bx, int& by) {
  const int bid = blockIdx.x;        // 0..511, 512 % 8 == 0
  const int xcd = bid & 7;
  const int loc = bid >> 3;          // 0..63
  const int cy = xcd >> 1;           // 0..3  chunk row
  const int cx = xcd & 1;            // 0..1  chunk col
  by = cy * 8 + (loc >> 3);          // 0..31
  bx = cx * 8 + (loc & 7);           // 0..15
}

// ---------------------------------------------------------------------------
// Fused persistent kernel: phase tile (by,bx) -> publish strip -> wait for
// strip by complete (16 tiles) -> gain tile (by,bx).
// Grid 512, launch_bounds(256,2), 64 KB LDS -> 2 blocks/CU, all co-resident
// (deadlock-free: producer work precedes any wait; release/acquire agent
// scope handles cross-XCD L2 visibility).
// ---------------------------------------------------------------------------
__global__ __launch_bounds__(256, 2) void phase_gain(
    const char* __restrict__ xf4, const char* __restrict__ ct4,
    u8* __restrict__ cs4, const char* __restrict__ ab4,
    const float* __restrict__ bias, float* __restrict__ out,
    u32* __restrict__ strip_done) {
  __shared__ __align__(16) char smem[65536];
  int bx, by;
  tile_xy(bx, by);
  const int rowA0 = by * 128;
  const int colB0 = bx * 128;
  const int lane = threadIdx.x & 63;
  const int wid = threadIdx.x >> 6;
  const int wr = wid >> 1, wc = wid & 1;

  // ---------------- phase tile ----------------
  {
    f32x4 acc[4][4];
#pragma unroll
    for (int m = 0; m < 4; ++m)
#pragma unroll
      for (int n = 0; n < 4; ++n)
#pragma unroll
        for (int j = 0; j < 4; ++j) acc[m][n][j] = 0.0f;

    gemm_kloop_fp4<0x7F7F7F7F, 0x7C7C7C7C>(xf4, ct4, rowA0, colB0, I_DIM / 2, smem,
                                           acc);

#pragma unroll
    for (int m = 0; m < 4; ++m) {
#pragma unroll
      for (int n = 0; n < 4; ++n) {
        const int col = colB0 + wc * 64 + n * 16 + (lane & 15);
#pragma unroll
        for (int j = 0; j < 4; ++j) {
          const int row = rowA0 + wr * 64 + m * 16 + (lane >> 4) * 4 + j;
          const float p = acc[m][n][j];
          float sp, cp;
          __sincosf(p, &sp, &cp);
          const u32 b = f2fp4(cp, 4.f) | (f2fp4(sp, 4.f) << 4);
          cs4[(long)row * H_DIM + col] = (u8)b;
        }
      }
    }
  }

  // ---------------- publish + wait for strip ----------------
  __threadfence();   // make this block's cs4 stores device-visible
  __syncthreads();
  if (threadIdx.x == 0) {
    __hip_atomic_fetch_add(&strip_done[by], 1u, __ATOMIC_ACQ_REL,
                           __HIP_MEMORY_SCOPE_AGENT);
    while (__hip_atomic_load(&strip_done[by], __ATOMIC_ACQUIRE,
                             __HIP_MEMORY_SCOPE_AGENT) < 16u)
      __builtin_amdgcn_s_sleep(1);
  }
  __syncthreads();
  __threadfence();   // acquire side: discard stale cs4 lines before reading

  // ---------------- gain tile ----------------
  {
    f32x4 acc[4][4];
#pragma unroll
    for (int m = 0; m < 4; ++m)
#pragma unroll
      for (int n = 0; n < 4; ++n)
#pragma unroll
        for (int j = 0; j < 4; ++j) acc[m][n][j] = 0.0f;

    gemm_kloop_fp4<0x7D7D7D7D, 0x7C7C7C7C>((const char*)cs4, ab4, rowA0, colB0,
                                           H_DIM, smem, acc);

#pragma unroll
    for (int m = 0; m < 4; ++m) {
#pragma unroll
      for (int n = 0; n < 4; ++n) {
        const int col = colB0 + wc * 64 + n * 16 + (lane & 15);
        const float bv = 2048.0f * bias[col];
#pragma unroll
        for (int j = 0; j < 4; ++j) {
          const int row = rowA0 + wr * 64 + m * 16 + (lane >> 4) * 4 + j;
          out[(long)row * I_DIM + col] = acc[m][n][j] + bv;
        }
      }
    }
  }
}

// ---------------------------------------------------------------------------
extern "C" void kernel_launch(void* const* d_in, const int* in_sizes, int n_in,
                              void* d_out, int out_size, void* d_ws, size_t ws_size,
                              hipStream_t stream) {
  const float* x     = (const float*)d_in[0];
  const float* coeff = (const float*)d_in[1];
  const float* an    = (const float*)d_in[2];
  const float* bn    = (const float*)d_in[3];
  const float* bias  = (const float*)d_in[4];
  float* out = (float*)d_out;

  char* ws = (char*)d_ws;
  char* xf4 = ws;                         //  4 MB  [B, I/2] fp4 (x, scale 1)
  char* ct4 = ws + (4L << 20);            //  2 MB  [H, I/2] fp4 (coeff^T x8)
  char* ab4 = ws + (8L << 20);            //  4 MB  [I, H]   fp4-pair (an|bn<<4)
  u8*  cs4  = (u8*)(ws + (12L << 20));    //  8 MB  [B, H]   fp4-pair (cos|sin<<4)
  u32* strip_done = (u32*)(ws + (20L << 20));  // 32 counters

  prep_all<<<1536, 256, 0, stream>>>(x, coeff, an, bn, (u16*)xf4, (u16*)ct4,
                                     (u32*)ab4, strip_done);
  phase_gain<<<512, 256, 0, stream>>>(xf4, ct4, cs4, (const char*)ab4, bias, out,
                                      strip_done);
}

// Round 19
// 62.467 us; speedup vs baseline: 2.6343x; 2.6343x over previous
//
#include <hip/hip_runtime.h>
#include <hip/hip_bf16.h>

#define B_DIM 4096
#define I_DIM 2048
#define H_DIM 2048

typedef unsigned char u8;
typedef unsigned short u16;
typedef unsigned int u32;
typedef __attribute__((ext_vector_type(4))) float f32x4;
typedef __attribute__((ext_vector_type(4))) int i32x4;
typedef __attribute__((ext_vector_type(8))) int i32x8;

#define SBAR __builtin_amdgcn_sched_barrier(0)
#define NBUF 49152  // per buffer: A (128r x 128B) @ 0, B (256r x 128B) @ 16384

__device__ __forceinline__ void gload_lds16(const void* g, void* l) {
  __builtin_amdgcn_global_load_lds(
      (const __attribute__((address_space(1))) void*)g,
      (__attribute__((address_space(3))) void*)l, 16, 0, 0);
}

// branchless fp4 (e2m1) encoder: quantizes v*inv_scale to e2m1 code
__device__ __forceinline__ u32 f2fp4(float v, float inv_scale) {
  const float a = fabsf(v) * inv_scale;
  u32 m = (u32)(a > 0.25f) + (u32)(a > 0.75f) + (u32)(a > 1.25f) +
          (u32)(a > 1.75f) + (u32)(a > 2.5f) + (u32)(a > 3.5f) + (u32)(a > 5.0f);
  return ((__float_as_uint(v) >> 31) << 3) | m;
}

// ---------------------------------------------------------------------------
// Kernel A (fused prep, R17-verified):
//  blocks [0, 512):     coeff -> coeffT fp4 (8 transpose tiles per block)
//  blocks [512, 1536):  x -> fp4 xf4; (an,bn) -> fp4-pair ab4
// ---------------------------------------------------------------------------
__global__ void prep_all(const float* __restrict__ x, const float* __restrict__ coeff,
                         const float* __restrict__ an, const float* __restrict__ bn,
                         u16* __restrict__ xf4, u16* __restrict__ ct4,
                         u32* __restrict__ ab4) {
  if (blockIdx.x < 512) {
    __shared__ float tile[32][33];
    const int tid = threadIdx.x;
    const int tx = tid & 31;
    const int ty = tid >> 5;
    const int hl = tid >> 3;
    const int q = (tid & 7) * 4;
#pragma unroll
    for (int rep = 0; rep < 8; ++rep) {
      const int tidx = blockIdx.x * 8 + rep;      // 0..4095
      const int h0 = (tidx & 63) * 32;
      const int i0 = (tidx >> 6) * 32;
      for (int r = ty; r < 32; r += 8)
        tile[r][tx] = coeff[(long)(i0 + r) * H_DIM + (h0 + tx)];
      __syncthreads();
      u32 w = f2fp4(tile[q + 0][hl], 8.f) | (f2fp4(tile[q + 1][hl], 8.f) << 4) |
              (f2fp4(tile[q + 2][hl], 8.f) << 8) | (f2fp4(tile[q + 3][hl], 8.f) << 12);
      ct4[(long)(h0 + hl) * (I_DIM / 4) + ((i0 + q) >> 2)] = (u16)w;
      __syncthreads();
    }
    return;
  }
  const long NX4 = (long)B_DIM * I_DIM / 4;
  const long NA4 = (long)I_DIM * H_DIM / 4;
  const long total = NX4 + NA4;
  const long stride = (long)1024 * blockDim.x;
  for (long t = (long)(blockIdx.x - 512) * blockDim.x + threadIdx.x; t < total;
       t += stride) {
    if (t < NX4) {
      float4 v = *(const float4*)(x + t * 4);
      u32 b0 = f2fp4(v.x, 1.f) | (f2fp4(v.y, 1.f) << 4);
      u32 b1 = f2fp4(v.z, 1.f) | (f2fp4(v.w, 1.f) << 4);
      xf4[t] = (u16)(b0 | (b1 << 8));
    } else {
      long p = (t - NX4) * 4;
      float4 va = *(const float4*)(an + p);
      float4 vb = *(const float4*)(bn + p);
      u32 b0 = f2fp4(va.x, 8.f) | (f2fp4(vb.x, 8.f) << 4);
      u32 b1 = f2fp4(va.y, 8.f) | (f2fp4(vb.y, 8.f) << 4);
      u32 b2 = f2fp4(va.z, 8.f) | (f2fp4(vb.z, 8.f) << 4);
      u32 b3 = f2fp4(va.w, 8.f) | (f2fp4(vb.w, 8.f) << 4);
      ab4[p >> 2] = b0 | (b1 << 8) | (b2 << 16) | (b3 << 24);
    }
  }
}

// ---------------------------------------------------------------------------
// 4-phase counted-lgkm fp4 kloop. BM=128, BN=256, K-step 128 B, 8 waves
// (2M x 4N), per-wave 64x64. Triple-buffered LDS (3 x 48 KB), depth-2
// prefetch, vmcnt(6) + ONE barrier per K-tile, read-ahead + counted
// lgkmcnt per phase (m201/m218 mechanism), XOR-swizzled LDS.
// Safety of single barrier: each wave's P3 lgkmcnt(0) precedes its barrier
// entry, so buffer b2 (read at t-1) is drained by ALL waves before any
// wave exits the tile-t TOP barrier and stages t+2 into it.
// ---------------------------------------------------------------------------
__device__ __forceinline__ void stageA2(const char* Ab, long kbyte, long lda,
                                        char* buf, int tid) {
#pragma unroll
  for (int i = 0; i < 2; ++i) {
    const int o = i * 8192 + tid * 16;
    const int row = o >> 7;
    const int ls = ((((o >> 4) & 7) ^ (row & 7)) << 4);
    gload_lds16(Ab + (long)row * lda + kbyte + ls, buf + o);
  }
}
__device__ __forceinline__ void stageB2(const char* Bb, long kbyte, long ldb,
                                        char* buf, int tid, int i0) {
#pragma unroll
  for (int i = 0; i < 2; ++i) {
    const int o = (i0 + i) * 8192 + tid * 16;
    const int row = o >> 7;
    const int ls = ((((o >> 4) & 7) ^ (row & 7)) << 4);
    gload_lds16(Bb + (long)row * ldb + kbyte + ls, buf + 16384 + o);
  }
}

__device__ __forceinline__ i32x4 frag_ld16(const char* S, int row, int slot) {
  return *(const i32x4*)(S + row * 128 + ((slot ^ (row & 7)) << 4));
}

template <int SA, int SB>
__device__ __forceinline__ void gemm_kloop_fp4(const char* __restrict__ A,
                                               const char* __restrict__ Bt,
                                               int rowA0, int colB0, long Kbytes,
                                               char* smem, f32x4 acc[4][4]) {
  const int tid = threadIdx.x;
  const int lane = tid & 63;
  const int wid = tid >> 6;   // 0..7
  const int wr = wid >> 2;    // 0..1 (M)
  const int wc = wid & 3;     // 0..3 (N)
  const long lda = Kbytes, ldb = Kbytes;
  const char* Ab = A + (long)rowA0 * lda;
  const char* Bb = Bt + (long)colB0 * ldb;
  const int arow = wr * 64 + (lane & 15);
  const int brow = wc * 64 + (lane & 15);
  const int g = lane >> 4;    // 0..3
  const int nt = (int)(Kbytes >> 7);

  char* b0 = smem;             // tile t (read)
  char* b1 = smem + NBUF;      // tile t+1 (landing)
  char* b2 = smem + 2 * NBUF;  // tile t+2 stage target (= read buffer of t-1)

  // prologue: stage tiles 0 and 1 (6 loads each)
  stageA2(Ab, 0, lda, b0, tid);   stageB2(Bb, 0, ldb, b0, tid, 0);
  stageB2(Bb, 0, ldb, b0, tid, 2);
  stageA2(Ab, 128, lda, b1, tid); stageB2(Bb, 128, ldb, b1, tid, 0);
  stageB2(Bb, 128, ldb, b1, tid, 2);

  for (int t = 0; t < nt; ++t) {
    if (t < nt - 1) asm volatile("s_waitcnt vmcnt(6)" ::: "memory");
    else            asm volatile("s_waitcnt vmcnt(0)" ::: "memory");
    SBAR;
    __builtin_amdgcn_s_barrier();
    SBAR;

    const bool st = (t + 2 < nt);
    const long kb2 = (long)(t + 2) * 128;
    i32x8 af[2][4], bfr[2][4];  // low i32x4 holds the fp4 operand

    // TOP: issue P0's 6 reads (af s0 x4, bfr s0 n0,n1); stage A x2
#pragma unroll
    for (int m = 0; m < 4; ++m)
      *(i32x4*)&af[0][m] = frag_ld16(b0, arow + m * 16, g);
    *(i32x4*)&bfr[0][0] = frag_ld16(b0 + 16384, brow, g);
    *(i32x4*)&bfr[0][1] = frag_ld16(b0 + 16384, brow + 16, g);
    if (st) stageA2(Ab, kb2, lda, b2, tid);
    SBAR;
    // issue P1's 2 reads (bfr s0 n2,n3)
    *(i32x4*)&bfr[0][2] = frag_ld16(b0 + 16384, brow + 32, g);
    *(i32x4*)&bfr[0][3] = frag_ld16(b0 + 16384, brow + 48, g);
    SBAR;
    // P0: drain the 6 (leave 2 in flight); MFMA s0 x n01
    asm volatile("s_waitcnt lgkmcnt(2)" ::: "memory");
    SBAR;
    __builtin_amdgcn_s_setprio(1);
#pragma unroll
    for (int m = 0; m < 4; ++m)
#pragma unroll
      for (int n = 0; n < 2; ++n)
        acc[m][n] = __builtin_amdgcn_mfma_scale_f32_16x16x128_f8f6f4(
            af[0][m], bfr[0][n], acc[m][n], 4, 4, 0, SA, 0, SB);
    __builtin_amdgcn_s_setprio(0);
    SBAR;

    // P1: issue P2's 6 reads (af s1 x4, bfr s1 n0,n1); stage B x2
#pragma unroll
    for (int m = 0; m < 4; ++m)
      *(i32x4*)&af[1][m] = frag_ld16(b0, arow + m * 16, 4 + g);
    *(i32x4*)&bfr[1][0] = frag_ld16(b0 + 16384, brow, 4 + g);
    *(i32x4*)&bfr[1][1] = frag_ld16(b0 + 16384, brow + 16, 4 + g);
    if (st) stageB2(Bb, kb2, ldb, b2, tid, 0);
    SBAR;
    asm volatile("s_waitcnt lgkmcnt(6)" ::: "memory");  // drain bfr[0][2,3]
    SBAR;
    __builtin_amdgcn_s_setprio(1);
#pragma unroll
    for (int m = 0; m < 4; ++m)
#pragma unroll
      for (int n = 2; n < 4; ++n)
        acc[m][n] = __builtin_amdgcn_mfma_scale_f32_16x16x128_f8f6f4(
            af[0][m], bfr[0][n], acc[m][n], 4, 4, 0, SA, 0, SB);
    __builtin_amdgcn_s_setprio(0);
    SBAR;

    // P2: issue P3's 2 reads (bfr s1 n2,n3); stage B x2
    *(i32x4*)&bfr[1][2] = frag_ld16(b0 + 16384, brow + 32, 4 + g);
    *(i32x4*)&bfr[1][3] = frag_ld16(b0 + 16384, brow + 48, 4 + g);
    if (st) stageB2(Bb, kb2, ldb, b2, tid, 2);
    SBAR;
    asm volatile("s_waitcnt lgkmcnt(2)" ::: "memory");  // drain P2's 6
    SBAR;
    __builtin_amdgcn_s_setprio(1);
#pragma unroll
    for (int m = 0; m < 4; ++m)
#pragma unroll
      for (int n = 0; n < 2; ++n)
        acc[m][n] = __builtin_amdgcn_mfma_scale_f32_16x16x128_f8f6f4(
            af[1][m], bfr[1][n], acc[m][n], 4, 4, 0, SA, 0, SB);
    __builtin_amdgcn_s_setprio(0);
    SBAR;

    // P3: drain all; MFMA s1 x n23
    asm volatile("s_waitcnt lgkmcnt(0)" ::: "memory");
    SBAR;
    __builtin_amdgcn_s_setprio(1);
#pragma unroll
    for (int m = 0; m < 4; ++m)
#pragma unroll
      for (int n = 2; n < 4; ++n)
        acc[m][n] = __builtin_amdgcn_mfma_scale_f32_16x16x128_f8f6f4(
            af[1][m], bfr[1][n], acc[m][n], 4, 4, 0, SA, 0, SB);
    __builtin_amdgcn_s_setprio(0);
    SBAR;

    char* tmp = b0; b0 = b1; b1 = b2; b2 = tmp;
  }
}

// Square-ish XCD chunking: 256 blocks over 32(by) x 8(bx); each XCD owns an
// 8(by) x 4(bx) chunk -> per-XCD working set = 2+2 MB, fits the 4 MB L2.
__device__ __forceinline__ void tile_xy(int& bx, int& by) {
  const int bid = blockIdx.x;   // 0..255, 256 % 8 == 0
  const int xcd = bid & 7;
  const int loc = bid >> 3;     // 0..31
  bx = (xcd & 1) * 4 + (loc & 3);    // 0..7
  by = (xcd >> 1) * 8 + (loc >> 2);  // 0..31
}

// ---------------------------------------------------------------------------
// Kernel C: GEMM1 (MX-fp4)  phase = x @ coeff ; epilogue -> fp4 (cos|sin<<4)
// A scale 2^0 (0x7F), B scale 2^-3 (0x7C)
// ---------------------------------------------------------------------------
__global__ __launch_bounds__(512, 2) void gemm_phase(const char* __restrict__ xf4,
                                                     const char* __restrict__ ct4,
                                                     u8* __restrict__ cs4) {
  __shared__ __align__(16) char smem[3 * NBUF];
  int bx, by;
  tile_xy(bx, by);
  const int rowA0 = by * 128;
  const int colB0 = bx * 256;
  f32x4 acc[4][4];
#pragma unroll
  for (int m = 0; m < 4; ++m)
#pragma unroll
    for (int n = 0; n < 4; ++n)
#pragma unroll
      for (int j = 0; j < 4; ++j) acc[m][n][j] = 0.0f;

  gemm_kloop_fp4<0x7F7F7F7F, 0x7C7C7C7C>(xf4, ct4, rowA0, colB0, I_DIM / 2, smem, acc);

  const int lane = threadIdx.x & 63;
  const int wid = threadIdx.x >> 6;
  const int wr = wid >> 2, wc = wid & 3;
#pragma unroll
  for (int m = 0; m < 4; ++m) {
#pragma unroll
    for (int n = 0; n < 4; ++n) {
      const int col = colB0 + wc * 64 + n * 16 + (lane & 15);
#pragma unroll
      for (int j = 0; j < 4; ++j) {
        const int row = rowA0 + wr * 64 + m * 16 + (lane >> 4) * 4 + j;
        const float p = acc[m][n][j];
        float sp, cp;
        __sincosf(p, &sp, &cp);
        const u32 b = f2fp4(cp, 4.f) | (f2fp4(sp, 4.f) << 4);
        cs4[(long)row * H_DIM + col] = (u8)b;
      }
    }
  }
}

// ---------------------------------------------------------------------------
// Kernel D: GEMM2 (MX-fp4)  gain = cs4 @ ab4^T + H*bias
// A scale 2^-2 (0x7D), B scale 2^-3 (0x7C)
// ---------------------------------------------------------------------------
__global__ __launch_bounds__(512, 2) void gemm_gain(const char* __restrict__ cs4,
                                                    const char* __restrict__ ab4,
                                                    const float* __restrict__ bias,
                                                    float* __restrict__ out) {
  __shared__ __align__(16) char smem[3 * NBUF];
  int bx, by;
  tile_xy(bx, by);
  const int rowA0 = by * 128;
  const int colB0 = bx * 256;
  f32x4 acc[4][4];
#pragma unroll
  for (int m = 0; m < 4; ++m)
#pragma unroll
    for (int n = 0; n < 4; ++n)
#pragma unroll
      for (int j = 0; j < 4; ++j) acc[m][n][j] = 0.0f;

  gemm_kloop_fp4<0x7D7D7D7D, 0x7C7C7C7C>(cs4, ab4, rowA0, colB0, H_DIM, smem, acc);

  const int lane = threadIdx.x & 63;
  const int wid = threadIdx.x >> 6;
  const int wr = wid >> 2, wc = wid & 3;
#pragma unroll
  for (int m = 0; m < 4; ++m) {
#pragma unroll
    for (int n = 0; n < 4; ++n) {
      const int col = colB0 + wc * 64 + n * 16 + (lane & 15);
      const float bv = 2048.0f * bias[col];
#pragma unroll
      for (int j = 0; j < 4; ++j) {
        const int row = rowA0 + wr * 64 + m * 16 + (lane >> 4) * 4 + j;
        out[(long)row * I_DIM + col] = acc[m][n][j] + bv;
      }
    }
  }
}

// ---------------------------------------------------------------------------
extern "C" void kernel_launch(void* const* d_in, const int* in_sizes, int n_in,
                              void* d_out, int out_size, void* d_ws, size_t ws_size,
                              hipStream_t stream) {
  const float* x     = (const float*)d_in[0];
  const float* coeff = (const float*)d_in[1];
  const float* an    = (const float*)d_in[2];
  const float* bn    = (const float*)d_in[3];
  const float* bias  = (const float*)d_in[4];
  float* out = (float*)d_out;

  char* ws = (char*)d_ws;
  char* xf4 = ws;                        //  4 MB  [B, I/2] fp4 (x, scale 1)
  char* ct4 = ws + (4L << 20);           //  2 MB  [H, I/2] fp4 (coeff^T x8)
  char* ab4 = ws + (8L << 20);           //  4 MB  [I, H]   fp4-pair (an|bn<<4)
  u8*  cs4  = (u8*)(ws + (12L << 20));   //  8 MB  [B, H]   fp4-pair (cos|sin<<4)

  prep_all<<<1536, 256, 0, stream>>>(x, coeff, an, bn, (u16*)xf4, (u16*)ct4,
                                     (u32*)ab4);
  gemm_phase<<<256, 512, 0, stream>>>(xf4, ct4, cs4);
  gemm_gain<<<256, 512, 0, stream>>>((const char*)cs4, (const char*)ab4, bias, out);
}